// Round 1
// baseline (216.133 us; speedup 1.0000x reference)
//
#include <hip/hip_runtime.h>

#define HID 32

// ---- count in-degree per node (same for all 3 layers) ----
__global__ void count_kernel(const int* __restrict__ dst, float* __restrict__ cnt, int E) {
    int e = blockIdx.x * blockDim.x + threadIdx.x;
    if (e < E) atomicAdd(cnt + dst[e], 1.0f);
}

// ---- fused NNConv edge pass: msg = x[src] . relu(ea@w_mlp+b), atomic scatter into agg ----
// 32 lanes per edge; lane = output channel. Per-lane weight column held in VGPRs,
// grid-stride over edges amortizes the 5*IN-dword weight preload.
template<int IN>
__global__ __launch_bounds__(256) void edge_kernel(
    const float* __restrict__ h_in,                 // [N, IN]
    const int* __restrict__ src, const int* __restrict__ dst,
    const float* __restrict__ ea,                   // [E, 4]
    const float* __restrict__ w_mlp,                // [4, IN*HID]
    const float* __restrict__ b_mlp,                // [IN*HID]
    float* __restrict__ agg,                        // [N, HID] (pre-zeroed)
    int E)
{
    const int lane = threadIdx.x & 31;              // output channel o
    const int grp  = (blockIdx.x * blockDim.x + threadIdx.x) >> 5;
    const int ngrp = (gridDim.x * blockDim.x) >> 5;

    // hoist this lane's weight column into registers: w[k][i*HID+lane], b[i*HID+lane]
    float w0[IN], w1[IN], w2[IN], w3[IN], br[IN];
    #pragma unroll
    for (int i = 0; i < IN; ++i) {
        int c = i * HID + lane;                     // coalesced across lanes
        w0[i] = w_mlp[c];
        w1[i] = w_mlp[IN * HID + c];
        w2[i] = w_mlp[2 * IN * HID + c];
        w3[i] = w_mlp[3 * IN * HID + c];
        br[i] = b_mlp[c];
    }

    for (int e = grp; e < E; e += ngrp) {
        int s = src[e], d = dst[e];
        float4 a = *(const float4*)(ea + (size_t)e * 4);    // broadcast within group
        const float* xs = h_in + (size_t)s * IN;
        float acc = 0.f;
        #pragma unroll
        for (int i = 0; i < IN; ++i) {
            float t = fmaf(a.x, w0[i], br[i]);
            t = fmaf(a.y, w1[i], t);
            t = fmaf(a.z, w2[i], t);
            t = fmaf(a.w, w3[i], t);
            t = fmaxf(t, 0.f);                      // relu of edge-MLP output
            acc = fmaf(xs[i], t, acc);              // xs[i] broadcast-load within group
        }
        atomicAdd(agg + (size_t)d * HID + lane, acc);
    }
}

// ---- node update: h_out = relu(agg/max(cnt,1) + x@root + bias) ----
template<int IN>
__global__ __launch_bounds__(256) void node_kernel(
    const float* __restrict__ x_in,                 // [N, IN]
    const float* __restrict__ agg,                  // [N, HID]
    const float* __restrict__ cnt,                  // [N]
    const float* __restrict__ root,                 // [IN, HID]
    const float* __restrict__ bias,                 // [HID]
    float* __restrict__ h_out,                      // [N, HID]
    int N)
{
    int idx = blockIdx.x * blockDim.x + threadIdx.x;
    int v = idx >> 5, o = idx & 31;
    if (v >= N) return;
    float r = bias[o];
    const float* xv = x_in + (size_t)v * IN;
    #pragma unroll
    for (int i = 0; i < IN; ++i)
        r = fmaf(xv[i], root[i * HID + o], r);      // root read coalesced across lanes
    float m = agg[(size_t)v * HID + o] / fmaxf(cnt[v], 1.0f);
    h_out[(size_t)v * HID + o] = fmaxf(m + r, 0.f);
}

// ---- output head: out = relu(h@w1+b1) @ w2 + b2 ----
__global__ __launch_bounds__(256) void head_kernel(
    const float* __restrict__ h,                    // [N, HID]
    const float* __restrict__ w1, const float* __restrict__ b1,  // [HID,HID],[HID]
    const float* __restrict__ w2, const float* __restrict__ b2,  // [HID,1],[1]
    float* __restrict__ out, int N)
{
    int idx = blockIdx.x * blockDim.x + threadIdx.x;
    int v = idx >> 5, o = idx & 31;
    if (v >= N) return;
    float t = b1[o];
    const float* hv = h + (size_t)v * HID;
    #pragma unroll
    for (int i = 0; i < HID; ++i)
        t = fmaf(hv[i], w1[i * HID + o], t);
    t = fmaxf(t, 0.f) * w2[o];
    // reduce over the 32-lane group
    #pragma unroll
    for (int d = 16; d > 0; d >>= 1)
        t += __shfl_down(t, d, 32);
    if (o == 0) out[v] = t + b2[0];
}

extern "C" void kernel_launch(void* const* d_in, const int* in_sizes, int n_in,
                              void* d_out, int out_size, void* d_ws, size_t ws_size,
                              hipStream_t stream)
{
    const float* x      = (const float*)d_in[0];
    const int*   ei     = (const int*)d_in[1];     // [2, E] int32
    const float* ea     = (const float*)d_in[2];
    const float* w_mlp1 = (const float*)d_in[3];
    const float* b_mlp1 = (const float*)d_in[4];
    const float* root1  = (const float*)d_in[5];
    const float* bias1  = (const float*)d_in[6];
    const float* w_mlp2 = (const float*)d_in[7];
    const float* b_mlp2 = (const float*)d_in[8];
    const float* root2  = (const float*)d_in[9];
    const float* bias2  = (const float*)d_in[10];
    const float* w_mlp3 = (const float*)d_in[11];
    const float* b_mlp3 = (const float*)d_in[12];
    const float* root3  = (const float*)d_in[13];
    const float* bias3  = (const float*)d_in[14];
    const float* w_out1 = (const float*)d_in[15];
    const float* b_out1 = (const float*)d_in[16];
    const float* w_out2 = (const float*)d_in[17];
    const float* b_out2 = (const float*)d_in[18];

    const int NODE_IN = 8;
    const int N = in_sizes[0] / NODE_IN;            // 25000
    const int E = in_sizes[2] / 4;                  // 100000
    const int* src = ei;
    const int* dst = ei + E;

    // workspace carve-up (re-poisoned to 0xAA each call -> must memset what needs zeros)
    char* ws = (char*)d_ws;
    size_t off = 0;
    auto carve = [&](size_t bytes) {
        char* p = ws + off;
        off += (bytes + 255) & ~(size_t)255;
        return p;
    };
    float* cnt = (float*)carve((size_t)N * 4);
    float* agg = (float*)carve((size_t)N * HID * 4);
    float* h1  = (float*)carve((size_t)N * HID * 4);
    float* h2  = (float*)carve((size_t)N * HID * 4);
    float* outp = (float*)d_out;

    const int TB = 256;
    const int nodeBlocks = (N * HID + TB - 1) / TB;     // 3125
    const int edgeBlocks = 1024;                        // grid-stride, ~12 edges/group
    const int cntBlocks  = (E + TB - 1) / TB;

    hipMemsetAsync(cnt, 0, (size_t)N * 4, stream);
    hipMemsetAsync(agg, 0, (size_t)N * HID * 4, stream);
    count_kernel<<<cntBlocks, TB, 0, stream>>>(dst, cnt, E);

    // conv1: IN=8
    edge_kernel<8><<<edgeBlocks, TB, 0, stream>>>(x, src, dst, ea, w_mlp1, b_mlp1, agg, E);
    node_kernel<8><<<nodeBlocks, TB, 0, stream>>>(x, agg, cnt, root1, bias1, h1, N);

    // conv2: IN=32
    hipMemsetAsync(agg, 0, (size_t)N * HID * 4, stream);
    edge_kernel<32><<<edgeBlocks, TB, 0, stream>>>(h1, src, dst, ea, w_mlp2, b_mlp2, agg, E);
    node_kernel<32><<<nodeBlocks, TB, 0, stream>>>(h1, agg, cnt, root2, bias2, h2, N);

    // conv3: IN=32 (reuse h1 as output)
    hipMemsetAsync(agg, 0, (size_t)N * HID * 4, stream);
    edge_kernel<32><<<edgeBlocks, TB, 0, stream>>>(h2, src, dst, ea, w_mlp3, b_mlp3, agg, E);
    node_kernel<32><<<nodeBlocks, TB, 0, stream>>>(h2, agg, cnt, root3, bias3, h1, N);

    // head
    head_kernel<<<nodeBlocks, TB, 0, stream>>>(h1, w_out1, b_out1, w_out2, b_out2, outp, N);
}

// Round 2
// 210.387 us; speedup vs baseline: 1.0273x; 1.0273x over previous
//
#include <hip/hip_runtime.h>

#define HID 32

// ---- fused NNConv edge pass: msg = x[src] . relu(ea@w_mlp+b), atomic scatter into agg ----
// 32 lanes per edge; lane = output channel. Per-lane weight column in VGPRs.
// Software-pipelined: next edge's (src,dst,ea,x-row) prefetched during compute.
// DO_COUNT: layer-1 also accumulates in-degree (lane 0).
template<int IN, bool DO_COUNT>
__global__ __launch_bounds__(256) void edge_kernel(
    const float* __restrict__ h_in,                 // [N, IN]
    const int* __restrict__ src, const int* __restrict__ dst,
    const float* __restrict__ ea,                   // [E, 4]
    const float* __restrict__ w_mlp,                // [4, IN*HID]
    const float* __restrict__ b_mlp,                // [IN*HID]
    float* __restrict__ agg,                        // [N, HID] (pre-zeroed)
    float* __restrict__ cnt,                        // [N] (pre-zeroed)
    int E)
{
    const int lane = threadIdx.x & 31;              // output channel o
    const int grp  = (blockIdx.x * blockDim.x + threadIdx.x) >> 5;
    const int ngrp = (gridDim.x * blockDim.x) >> 5;

    // hoist this lane's weight column into registers
    float w0[IN], w1[IN], w2[IN], w3[IN], br[IN];
    #pragma unroll
    for (int i = 0; i < IN; ++i) {
        int c = i * HID + lane;                     // coalesced across lanes
        w0[i] = w_mlp[c];
        w1[i] = w_mlp[IN * HID + c];
        w2[i] = w_mlp[2 * IN * HID + c];
        w3[i] = w_mlp[3 * IN * HID + c];
        br[i] = b_mlp[c];
    }

    int e = grp;
    if (e >= E) return;
    int s = src[e], d = dst[e];
    float4 a = *(const float4*)(ea + (size_t)e * 4);
    float4 xv[IN / 4];
    #pragma unroll
    for (int q = 0; q < IN / 4; ++q)
        xv[q] = *(const float4*)(h_in + (size_t)s * IN + q * 4);

    while (true) {
        // ---- prefetch next edge (overlaps the FMA block below) ----
        const int e2 = e + ngrp;
        const bool more = (e2 < E);
        int s2 = 0, d2 = 0;
        float4 a2 = make_float4(0.f, 0.f, 0.f, 0.f);
        float4 xv2[IN / 4];
        if (more) {
            s2 = src[e2]; d2 = dst[e2];
            a2 = *(const float4*)(ea + (size_t)e2 * 4);
            #pragma unroll
            for (int q = 0; q < IN / 4; ++q)
                xv2[q] = *(const float4*)(h_in + (size_t)s2 * IN + q * 4);
        }

        // ---- compute current edge ----
        float acc = 0.f;
        #pragma unroll
        for (int q = 0; q < IN / 4; ++q) {
            const float xs[4] = { xv[q].x, xv[q].y, xv[q].z, xv[q].w };
            #pragma unroll
            for (int j = 0; j < 4; ++j) {
                const int i = q * 4 + j;
                float t = fmaf(a.x, w0[i], br[i]);
                t = fmaf(a.y, w1[i], t);
                t = fmaf(a.z, w2[i], t);
                t = fmaf(a.w, w3[i], t);
                t = fmaxf(t, 0.f);                  // relu of edge-MLP output
                acc = fmaf(xs[j], t, acc);
            }
        }
        atomicAdd(agg + (size_t)d * HID + lane, acc);
        if (DO_COUNT && lane == 0) atomicAdd(cnt + d, 1.0f);

        if (!more) break;
        e = e2; s = s2; d = d2; a = a2;
        #pragma unroll
        for (int q = 0; q < IN / 4; ++q) xv[q] = xv2[q];
    }
    (void)s;
}

// ---- node update: h_out = relu(agg/max(cnt,1) + x@root + bias); optionally re-zero agg ----
template<int IN, bool ZERO_AGG>
__global__ __launch_bounds__(256) void node_kernel(
    const float* __restrict__ x_in,                 // [N, IN]
    float* __restrict__ agg,                        // [N, HID]
    const float* __restrict__ cnt,                  // [N]
    const float* __restrict__ root,                 // [IN, HID]
    const float* __restrict__ bias,                 // [HID]
    float* __restrict__ h_out,                      // [N, HID]
    int N)
{
    int idx = blockIdx.x * blockDim.x + threadIdx.x;
    int v = idx >> 5, o = idx & 31;
    if (v >= N) return;
    float r = bias[o];
    const float* xv = x_in + (size_t)v * IN;
    #pragma unroll
    for (int i = 0; i < IN; ++i)
        r = fmaf(xv[i], root[i * HID + o], r);      // root read coalesced across lanes
    float m = agg[(size_t)v * HID + o] / fmaxf(cnt[v], 1.0f);
    if (ZERO_AGG) agg[(size_t)v * HID + o] = 0.f;   // ready for next layer's edge pass
    h_out[(size_t)v * HID + o] = fmaxf(m + r, 0.f);
}

// ---- fused conv3 node update + output head (h3 never materialized) ----
__global__ __launch_bounds__(256) void node_head_kernel(
    const float* __restrict__ x_in,                 // h2 [N, HID]
    const float* __restrict__ agg,                  // [N, HID]
    const float* __restrict__ cnt,                  // [N]
    const float* __restrict__ root,                 // [HID, HID]
    const float* __restrict__ bias,                 // [HID]
    const float* __restrict__ w1, const float* __restrict__ b1,  // [HID,HID],[HID]
    const float* __restrict__ w2, const float* __restrict__ b2,  // [HID,1],[1]
    float* __restrict__ out, int N)
{
    int idx = blockIdx.x * blockDim.x + threadIdx.x;
    int v = idx >> 5, o = idx & 31;
    if (v >= N) return;
    float r = bias[o];
    const float* xv = x_in + (size_t)v * HID;
    #pragma unroll
    for (int i = 0; i < HID; ++i)
        r = fmaf(xv[i], root[i * HID + o], r);
    float m = agg[(size_t)v * HID + o] / fmaxf(cnt[v], 1.0f);
    float h = fmaxf(m + r, 0.f);                    // h3[v][o], lane-resident

    float t = b1[o];
    #pragma unroll
    for (int i = 0; i < HID; ++i)
        t = fmaf(__shfl(h, i, 32), w1[i * HID + o], t);
    t = fmaxf(t, 0.f) * w2[o];
    #pragma unroll
    for (int dd = 16; dd > 0; dd >>= 1)
        t += __shfl_down(t, dd, 32);
    if (o == 0) out[v] = t + b2[0];
}

extern "C" void kernel_launch(void* const* d_in, const int* in_sizes, int n_in,
                              void* d_out, int out_size, void* d_ws, size_t ws_size,
                              hipStream_t stream)
{
    const float* x      = (const float*)d_in[0];
    const int*   ei     = (const int*)d_in[1];     // [2, E] int32
    const float* ea     = (const float*)d_in[2];
    const float* w_mlp1 = (const float*)d_in[3];
    const float* b_mlp1 = (const float*)d_in[4];
    const float* root1  = (const float*)d_in[5];
    const float* bias1  = (const float*)d_in[6];
    const float* w_mlp2 = (const float*)d_in[7];
    const float* b_mlp2 = (const float*)d_in[8];
    const float* root2  = (const float*)d_in[9];
    const float* bias2  = (const float*)d_in[10];
    const float* w_mlp3 = (const float*)d_in[11];
    const float* b_mlp3 = (const float*)d_in[12];
    const float* root3  = (const float*)d_in[13];
    const float* bias3  = (const float*)d_in[14];
    const float* w_out1 = (const float*)d_in[15];
    const float* b_out1 = (const float*)d_in[16];
    const float* w_out2 = (const float*)d_in[17];
    const float* b_out2 = (const float*)d_in[18];

    const int NODE_IN = 8;
    const int N = in_sizes[0] / NODE_IN;            // 25000
    const int E = in_sizes[2] / 4;                  // 100000
    const int* src = ei;
    const int* dst = ei + E;

    // workspace carve-up: cnt and agg contiguous so ONE memset zeroes both
    char* ws = (char*)d_ws;
    size_t off = 0;
    auto carve = [&](size_t bytes) {
        char* p = ws + off;
        off += (bytes + 255) & ~(size_t)255;
        return p;
    };
    float* cnt = (float*)carve((size_t)N * 4);
    float* agg = (float*)carve((size_t)N * HID * 4);
    size_t zero_bytes = (size_t)((char*)agg - (char*)cnt) + (size_t)N * HID * 4;
    float* h1  = (float*)carve((size_t)N * HID * 4);
    float* h2  = (float*)carve((size_t)N * HID * 4);
    float* outp = (float*)d_out;

    const int TB = 256;
    const int nodeBlocks = (N * HID + TB - 1) / TB;     // 3125
    const int edgeBlocks = 512;                         // 2 blocks/CU residency at ~230 VGPR

    // 1) zero cnt+agg in one shot
    hipMemsetAsync(cnt, 0, zero_bytes, stream);

    // 2) conv1 edge pass (IN=8) + in-degree count
    edge_kernel<8, true><<<edgeBlocks, TB, 0, stream>>>(x, src, dst, ea, w_mlp1, b_mlp1, agg, cnt, E);
    // 3) conv1 node update, re-zero agg for conv2
    node_kernel<8, true><<<nodeBlocks, TB, 0, stream>>>(x, agg, cnt, root1, bias1, h1, N);

    // 4) conv2 edge pass (IN=32)
    edge_kernel<32, false><<<edgeBlocks, TB, 0, stream>>>(h1, src, dst, ea, w_mlp2, b_mlp2, agg, cnt, E);
    // 5) conv2 node update, re-zero agg for conv3
    node_kernel<32, true><<<nodeBlocks, TB, 0, stream>>>(h1, agg, cnt, root2, bias2, h2, N);

    // 6) conv3 edge pass (IN=32)
    edge_kernel<32, false><<<edgeBlocks, TB, 0, stream>>>(h2, src, dst, ea, w_mlp3, b_mlp3, agg, cnt, E);
    // 7) conv3 node update fused with output head
    node_head_kernel<<<nodeBlocks, TB, 0, stream>>>(h2, agg, cnt, root3, bias3,
                                                    w_out1, b_out1, w_out2, b_out2, outp, N);
}